// Round 9
// baseline (1135.874 us; speedup 1.0000x reference)
//
#include <hip/hip_runtime.h>
#include <math.h>

#define BB 8
#define NN 1024
#define LLAYERS 8

typedef unsigned short ushort_t;
typedef unsigned int uint_t;
using bf16x8 = __attribute__((ext_vector_type(8))) short;
using f32x4  = __attribute__((ext_vector_type(4))) float;

__constant__ int d_GRADE[16] = {0,1,1,1,1,2,2,2,2,2,2,3,3,3,3,4};
__constant__ int d_PAIR[16]  = {-1,0,-1,-1,-1,2,3,4,-1,-1,-1,8,9,10,-1,14};
__constant__ int d_IB[8] = {0,2,3,4,8,9,10,14};
__constant__ int d_I2M[16] = {0,1,2,4,8,3,5,9,6,10,12,7,11,13,14,15};
__constant__ int d_M2I[16] = {0,1,2,5,3,6,8,11,4,7,9,12,10,13,14,15};

#define QSCALE (0.22360679774997896f * 1.4426950408889634f)

// gelu(x)=0.5x(1+tanh(y)) = x/(1+exp(-2y)), y=0.79788456(x+0.044715x^3)
__device__ __forceinline__ float gelu_tanh(float x) {
  float y = 0.7978845608028654f * (x + 0.044715f * x * x * x);
  float e2 = __builtin_amdgcn_exp2f(y * -2.8853900817779268f);
  return x * __builtin_amdgcn_rcpf(1.0f + e2);
}

__device__ __forceinline__ ushort_t f2b(float f) {
  union { float f; unsigned int u; } x;
  x.f = f;
  unsigned int r = x.u + 0x7fffu + ((x.u >> 16) & 1u);  // RNE
  return (ushort_t)(r >> 16);
}

// ---------------- embed ----------------
__global__ void __launch_bounds__(256) k_embed(
    const float* __restrict__ inp, const float* __restrict__ win_mv,
    const float* __restrict__ win_ms, const float* __restrict__ win_bs,
    float* __restrict__ mv, float* __restrict__ s)
{
  int tok = blockIdx.x, t = threadIdx.x;
  float x = inp[tok * 3 + 0];
  float y = inp[tok * 3 + 1];
  float z = inp[tok * 3 + 2];
  int o = t >> 4, aa = t & 15;
  float ma = (aa == 14) ? 1.f : (aa == 13) ? -x : (aa == 12) ? y : (aa == 11) ? -z : 0.f;
  int g = d_GRADE[aa];
  float val = win_mv[o * 9 + g] * ma;
  int pr = d_PAIR[aa];
  if (pr >= 0) {
    float mp = (pr == 14) ? 1.f : 0.f;
    val += win_mv[o * 9 + 4 + g] * mp;
  }
  mv[(size_t)tok * 256 + t] = val;
  if (t < 32) s[(size_t)tok * 32 + t] = win_bs[t];
  (void)win_ms;
}

// ---------------- LN + QKV projection, 8-token tile (R7 version) ----------------
__global__ void __launch_bounds__(256) k_ln_qkv(
    const float* __restrict__ mv, const float* __restrict__ s,
    const float* __restrict__ wmv, const float* __restrict__ wsm,
    const float* __restrict__ wms, const float* __restrict__ wss,
    ushort_t* __restrict__ q_bf, ushort_t* __restrict__ k_bf, ushort_t* __restrict__ vT)
{
  __shared__ float pool[9600];
  float* xmv = pool;           // [8][256]
  float* xs  = pool + 2048;    // [8][32]
  float* yst = pool + 2304;    // [8][48] rows, stride 17
  float* sst = pool + 8832;    // [8][96]

  int t = threadIdx.x;
  int tok0 = blockIdx.x * 8;
  int b = tok0 >> 10, n0 = tok0 & 1023;
  int a = t & 15, og = t >> 4;
  int g = d_GRADE[a], pr = d_PAIR[a];

  float wgq[16], wpq[16], wgk[16], wpk[16], wgv[16], wpv[16];
  #pragma unroll
  for (int i = 0; i < 16; ++i) {
    wgq[i] = wmv[(og)      * 144 + i * 9 + g];
    wgk[i] = wmv[(16 + og) * 144 + i * 9 + g];
    wgv[i] = wmv[(32 + og) * 144 + i * 9 + g];
    wpq[i] = wmv[(og)      * 144 + i * 9 + 4 + g];
    wpk[i] = wmv[(16 + og) * 144 + i * 9 + 4 + g];
    wpv[i] = wmv[(32 + og) * 144 + i * 9 + 4 + g];
  }

  #pragma unroll
  for (int j = 0; j < 2; ++j)
    *(float4*)&xmv[t * 4 + j * 1024] = *(const float4*)&mv[(size_t)tok0 * 256 + t * 4 + j * 1024];
  if (t < 64)
    *(float4*)&xs[t * 4] = *(const float4*)&s[(size_t)tok0 * 32 + t * 4];
  __syncthreads();

  if (t < 128) {
    int tk = t >> 4, ch = t & 15;
    float* xp = &xmv[tk * 256 + ch * 16];
    float4 v0 = *(float4*)&xp[0], v1 = *(float4*)&xp[4];
    float4 v2 = *(float4*)&xp[8], v3 = *(float4*)&xp[12];
    float ss = v0.x*v0.x + v0.z*v0.z + v0.w*v0.w + v1.x*v1.x
             + v2.x*v2.x + v2.y*v2.y + v2.z*v2.z + v3.z*v3.z;
    ss += __shfl_xor(ss, 1); ss += __shfl_xor(ss, 2);
    ss += __shfl_xor(ss, 4); ss += __shfl_xor(ss, 8);
    float inv = rsqrtf(ss / 16.f + 1e-6f);
    v0.x*=inv; v0.y*=inv; v0.z*=inv; v0.w*=inv;
    v1.x*=inv; v1.y*=inv; v1.z*=inv; v1.w*=inv;
    v2.x*=inv; v2.y*=inv; v2.z*=inv; v2.w*=inv;
    v3.x*=inv; v3.y*=inv; v3.z*=inv; v3.w*=inv;
    *(float4*)&xp[0] = v0; *(float4*)&xp[4] = v1;
    *(float4*)&xp[8] = v2; *(float4*)&xp[12] = v3;
    float s0 = xs[tk * 32 + ch * 2], s1 = xs[tk * 32 + ch * 2 + 1];
    float s2 = s0 * s0 + s1 * s1;
    s2 += __shfl_xor(s2, 1); s2 += __shfl_xor(s2, 2);
    s2 += __shfl_xor(s2, 4); s2 += __shfl_xor(s2, 8);
    float sinv = rsqrtf(s2 / 32.f + 1e-6f);
    xs[tk * 32 + ch * 2] = s0 * sinv;
    xs[tk * 32 + ch * 2 + 1] = s1 * sinv;
  }
  __syncthreads();

  for (int tk = 0; tk < 8; ++tk) {
    float y0 = 0.f, y1 = 0.f, y2 = 0.f;
    const float* xb = &xmv[tk * 256];
    #pragma unroll
    for (int i = 0; i < 16; ++i) {
      float xa_ = xb[i * 16 + a];
      y0 += wgq[i] * xa_; y1 += wgk[i] * xa_; y2 += wgv[i] * xa_;
    }
    if (pr >= 0) {
      #pragma unroll
      for (int i = 0; i < 16; ++i) {
        float xp_ = xb[i * 16 + pr];
        y0 += wpq[i] * xp_; y1 += wpk[i] * xp_; y2 += wpv[i] * xp_;
      }
    }
    yst[(tk * 48 + og) * 17 + a] = y0;
    yst[(tk * 48 + 16 + og) * 17 + a] = y1;
    yst[(tk * 48 + 32 + og) * 17 + a] = y2;
  }
  __syncthreads();

  for (int u = t; u < 384; u += 256) {
    int tk = u / 48, o = u % 48;
    float add = 0.f;
    #pragma unroll
    for (int j = 0; j < 32; ++j) add += wsm[o * 32 + j] * xs[tk * 32 + j];
    yst[(tk * 48 + o) * 17 + 0] += add;
  }
  for (int u = t; u < 768; u += 256) {
    int tk = u / 96, o96 = u % 96;
    float yy = 0.f;
    #pragma unroll
    for (int j = 0; j < 32; ++j) yy += wss[o96 * 32 + j] * xs[tk * 32 + j];
    #pragma unroll
    for (int i = 0; i < 16; ++i) yy += wms[o96 * 16 + i] * xmv[tk * 256 + i * 16];
    sst[tk * 96 + o96] = yy;
  }
  __syncthreads();

  if (t < 128) {
    int isK = t >> 6;
    int r = t & 63;
    int tk = r >> 3, h = r & 7;
    float scale = isK ? 1.f : QSCALE;
    const float* base = &yst[(tk * 48 + isK * 16) * 17];
    ushort_t tmp[32];
    #pragma unroll
    for (int j = 0; j < 8; ++j) {
      int blade = d_IB[j];
      tmp[j]     = f2b(base[(2 * h)     * 17 + blade] * scale);
      tmp[8 + j] = f2b(base[(2 * h + 1) * 17 + blade] * scale);
    }
    #pragma unroll
    for (int d = 0; d < 4; ++d)
      tmp[16 + d] = f2b(sst[tk * 96 + isK * 32 + h * 4 + d] * scale);
    #pragma unroll
    for (int j2 = 20; j2 < 32; ++j2) tmp[j2] = 0;
    uint_t out[16];
    #pragma unroll
    for (int j3 = 0; j3 < 16; ++j3)
      out[j3] = (uint_t)tmp[2 * j3] | ((uint_t)tmp[2 * j3 + 1] << 16);
    ushort_t* dst = (isK ? k_bf : q_bf) + ((size_t)(b * 8 + h) * 1024 + n0 + tk) * 32;
    *(uint4*)(dst +  0) = make_uint4(out[0],  out[1],  out[2],  out[3]);
    *(uint4*)(dst +  8) = make_uint4(out[4],  out[5],  out[6],  out[7]);
    *(uint4*)(dst + 16) = make_uint4(out[8],  out[9],  out[10], out[11]);
    *(uint4*)(dst + 24) = make_uint4(out[12], out[13], out[14], out[15]);
  }
  {
    int h = t >> 5, dim = t & 31;
    int ch = 2 * h + (dim >> 4), blade = dim & 15;
    uint_t ov[4];
    #pragma unroll
    for (int tk = 0; tk < 8; ++tk) {
      ushort_t bv = f2b(yst[(tk * 48 + 32 + ch) * 17 + blade]);
      if (tk & 1) ov[tk >> 1] |= ((uint_t)bv) << 16; else ov[tk >> 1] = bv;
    }
    ushort_t* dst = vT + ((size_t)(b * 8 + h) * 48 + dim) * 1024 + n0;
    *(uint4*)dst = make_uint4(ov[0], ov[1], ov[2], ov[3]);
  }
  if (t < 32) {
    int h = t >> 2, d = t & 3;
    uint_t ov[4];
    #pragma unroll
    for (int tk = 0; tk < 8; ++tk) {
      ushort_t bv = f2b(sst[tk * 96 + 64 + h * 4 + d]);
      if (tk & 1) ov[tk >> 1] |= ((uint_t)bv) << 16; else ov[tk >> 1] = bv;
    }
    ushort_t* dst = vT + ((size_t)(b * 8 + h) * 48 + 32 + d) * 1024 + n0;
    *(uint4*)dst = make_uint4(ov[0], ov[1], ov[2], ov[3]);
  }
  if (t < 8) {
    ushort_t* dst = vT + ((size_t)(b * 8 + t) * 48 + 36) * 1024 + n0;
    *(uint4*)dst = make_uint4(0x3F803F80u, 0x3F803F80u, 0x3F803F80u, 0x3F803F80u);
  }
}

// ---------------- attention: bf16 MFMA, LDS-staged K/V (R7 version) ---------------
#define OPART_STRIDE 2359296
#define LPART_STRIDE 65536
__global__ void __launch_bounds__(256) k_attn(
    const ushort_t* __restrict__ q_bf, const ushort_t* __restrict__ k_bf,
    const ushort_t* __restrict__ vT, float* __restrict__ o_mvA, float* __restrict__ lA)
{
  __shared__ __align__(16) ushort_t kst[64 * 40];
  __shared__ __align__(16) ushort_t vst[48 * 72];
  __shared__ __align__(16) ushort_t plds[4][1280];
  int bx = blockIdx.x;
  int bh = bx & 63, qg = bx >> 6;
  int qb = qg & 15, kg = qg >> 4;
  int b = bh >> 3, h = bh & 7;
  int t = threadIdx.x;
  int w = t >> 6, lane = t & 63;
  int quad = lane >> 4, col = lane & 15;
  int q16 = qb * 64 + w * 16;
  size_t hb = (size_t)bh * 1024;
  ushort_t* myp = &plds[w][0];

  float* o_mvp = o_mvA + (size_t)kg * OPART_STRIDE;
  float* o_sp  = o_mvp + 2097152;
  float* l_p   = lA + (size_t)kg * LPART_STRIDE;

  bf16x8 qfrag = *(const bf16x8*)(q_bf + (hb + q16 + col) * 32 + quad * 8);

  f32x4 ot0 = {0.f,0.f,0.f,0.f}, ot1 = {0.f,0.f,0.f,0.f}, ot2 = {0.f,0.f,0.f,0.f};

  const ushort_t* kbase = k_bf + hb * 32;
  const ushort_t* vbase = vT + (size_t)bh * 48 * 1024;
  int k0 = kg * 512;

  int skey = t >> 2, sc4 = t & 3;
  for (int kt = 0; kt < 8; ++kt) {
    int kb = k0 + kt * 64;
    __syncthreads();
    *(uint4*)&kst[skey * 40 + sc4 * 8] =
        *(const uint4*)(kbase + (size_t)(kb + skey) * 32 + sc4 * 8);
    for (int u = t; u < 296; u += 256) {
      int row = u >> 3, c8 = u & 7;
      *(uint4*)&vst[row * 72 + c8 * 8] =
          *(const uint4*)(vbase + (size_t)row * 1024 + kb + c8 * 8);
    }
    __syncthreads();

    bf16x8 sk0 = *(const bf16x8*)&kst[(     col) * 40 + quad * 8];
    bf16x8 sk1 = *(const bf16x8*)&kst[(16 + col) * 40 + quad * 8];
    bf16x8 sk2 = *(const bf16x8*)&kst[(32 + col) * 40 + quad * 8];
    bf16x8 sk3 = *(const bf16x8*)&kst[(48 + col) * 40 + quad * 8];
    bf16x8 va0 = *(const bf16x8*)&vst[(     col) * 72 + quad * 8];
    bf16x8 va1 = *(const bf16x8*)&vst[(16 + col) * 72 + quad * 8];
    bf16x8 va2 = *(const bf16x8*)&vst[(32 + col) * 72 + quad * 8];
    bf16x8 vb0 = *(const bf16x8*)&vst[(     col) * 72 + 32 + quad * 8];
    bf16x8 vb1 = *(const bf16x8*)&vst[(16 + col) * 72 + 32 + quad * 8];
    bf16x8 vb2 = *(const bf16x8*)&vst[(32 + col) * 72 + 32 + quad * 8];
    f32x4 zero = {0.f,0.f,0.f,0.f};
    f32x4 sa0 = __builtin_amdgcn_mfma_f32_16x16x32_bf16(sk0, qfrag, zero, 0, 0, 0);
    f32x4 sa1 = __builtin_amdgcn_mfma_f32_16x16x32_bf16(sk1, qfrag, zero, 0, 0, 0);
    f32x4 sb0 = __builtin_amdgcn_mfma_f32_16x16x32_bf16(sk2, qfrag, zero, 0, 0, 0);
    f32x4 sb1 = __builtin_amdgcn_mfma_f32_16x16x32_bf16(sk3, qfrag, zero, 0, 0, 0);

    union { float f; uint_t u; } e0, e1, e2, e3;
    e0.f = __builtin_amdgcn_exp2f(sa0[0]); e1.f = __builtin_amdgcn_exp2f(sa0[1]);
    e2.f = __builtin_amdgcn_exp2f(sa0[2]); e3.f = __builtin_amdgcn_exp2f(sa0[3]);
    uint_t a0 = __builtin_amdgcn_perm(e1.u, e0.u, 0x07060302u);
    uint_t a1 = __builtin_amdgcn_perm(e3.u, e2.u, 0x07060302u);
    e0.f = __builtin_amdgcn_exp2f(sa1[0]); e1.f = __builtin_amdgcn_exp2f(sa1[1]);
    e2.f = __builtin_amdgcn_exp2f(sa1[2]); e3.f = __builtin_amdgcn_exp2f(sa1[3]);
    uint_t a2 = __builtin_amdgcn_perm(e1.u, e0.u, 0x07060302u);
    uint_t a3 = __builtin_amdgcn_perm(e3.u, e2.u, 0x07060302u);
    e0.f = __builtin_amdgcn_exp2f(sb0[0]); e1.f = __builtin_amdgcn_exp2f(sb0[1]);
    e2.f = __builtin_amdgcn_exp2f(sb0[2]); e3.f = __builtin_amdgcn_exp2f(sb0[3]);
    uint_t b0 = __builtin_amdgcn_perm(e1.u, e0.u, 0x07060302u);
    uint_t b1 = __builtin_amdgcn_perm(e3.u, e2.u, 0x07060302u);
    e0.f = __builtin_amdgcn_exp2f(sb1[0]); e1.f = __builtin_amdgcn_exp2f(sb1[1]);
    e2.f = __builtin_amdgcn_exp2f(sb1[2]); e3.f = __builtin_amdgcn_exp2f(sb1[3]);
    uint_t b2 = __builtin_amdgcn_perm(e1.u, e0.u, 0x07060302u);
    uint_t b3 = __builtin_amdgcn_perm(e3.u, e2.u, 0x07060302u);

    *(uint2*)(myp + col * 40 + quad * 4)            = make_uint2(a0, a1);
    *(uint2*)(myp + col * 40 + 16 + quad * 4)       = make_uint2(a2, a3);
    *(uint2*)(myp + 640 + col * 40 + quad * 4)      = make_uint2(b0, b1);
    *(uint2*)(myp + 640 + col * 40 + 16 + quad * 4) = make_uint2(b2, b3);
    __builtin_amdgcn_wave_barrier();
    bf16x8 pfa = *(const bf16x8*)(myp + col * 40 + quad * 8);
    bf16x8 pfb = *(const bf16x8*)(myp + 640 + col * 40 + quad * 8);
    __builtin_amdgcn_wave_barrier();
    ot0 = __builtin_amdgcn_mfma_f32_16x16x32_bf16(va0, pfa, ot0, 0, 0, 0);
    ot1 = __builtin_amdgcn_mfma_f32_16x16x32_bf16(va1, pfa, ot1, 0, 0, 0);
    ot2 = __builtin_amdgcn_mfma_f32_16x16x32_bf16(va2, pfa, ot2, 0, 0, 0);
    ot0 = __builtin_amdgcn_mfma_f32_16x16x32_bf16(vb0, pfb, ot0, 0, 0, 0);
    ot1 = __builtin_amdgcn_mfma_f32_16x16x32_bf16(vb1, pfb, ot1, 0, 0, 0);
    ot2 = __builtin_amdgcn_mfma_f32_16x16x32_bf16(vb2, pfb, ot2, 0, 0, 0);
  }

  int tok = b * NN + q16 + col;
  float* op0 = o_mvp + (size_t)tok * 256 + (2 * h) * 16 + quad * 4;
  op0[0] = ot0[0]; op0[1] = ot0[1]; op0[2] = ot0[2]; op0[3] = ot0[3];
  float* op1 = o_mvp + (size_t)tok * 256 + (2 * h + 1) * 16 + quad * 4;
  op1[0] = ot1[0]; op1[1] = ot1[1]; op1[2] = ot1[2]; op1[3] = ot1[3];
  if (quad == 0) {
    float* osp = o_sp + (size_t)tok * 32 + h * 4;
    osp[0] = ot2[0]; osp[1] = ot2[1]; osp[2] = ot2[2]; osp[3] = ot2[3];
  }
  if (quad == 1) l_p[hb + q16 + col] = ot2[0];
}

// ---------------- attention combine + out-proj + residual (R7 version) ------------
__global__ void __launch_bounds__(256) k_out_res(
    const float* __restrict__ o_mvA, const float* __restrict__ lA,
    const float* __restrict__ wmv, const float* __restrict__ wsm,
    const float* __restrict__ wms, const float* __restrict__ wss,
    float* __restrict__ mv, float* __restrict__ s)
{
  __shared__ float pool[4544];
  float* xo    = pool;          // [8][256]
  float* xso   = pool + 2048;   // [8][32]
  float* yst   = pool + 2304;   // [8][16] rows, stride 17
  float* invls = pool + 4480;   // [8][8]

  const float* o_sA  = o_mvA + 2097152;
  const float* o_mvB = o_mvA + OPART_STRIDE;
  const float* o_sB  = o_mvB + 2097152;
  const float* lB    = lA + LPART_STRIDE;

  int t = threadIdx.x;
  int tok0 = blockIdx.x * 8;
  int b8 = (tok0 >> 10) * 8, n0 = tok0 & 1023;
  int a = t & 15, og = t >> 4;
  int g = d_GRADE[a], pr = d_PAIR[a];

  float wg[16], wp[16];
  #pragma unroll
  for (int i = 0; i < 16; ++i) {
    wg[i] = wmv[og * 144 + i * 9 + g];
    wp[i] = wmv[og * 144 + i * 9 + 4 + g];
  }

  float4 ra[2], rc[2];
  #pragma unroll
  for (int j = 0; j < 2; ++j) {
    ra[j] = *(const float4*)&o_mvA[(size_t)tok0 * 256 + t * 4 + j * 1024];
    rc[j] = *(const float4*)&o_mvB[(size_t)tok0 * 256 + t * 4 + j * 1024];
  }
  float4 sa4 = {0,0,0,0}, sc4 = {0,0,0,0};
  if (t < 64) {
    int tk = t >> 3, h = t & 7;
    sa4 = *(const float4*)&o_sA[(size_t)(tok0 + tk) * 32 + h * 4];
    sc4 = *(const float4*)&o_sB[(size_t)(tok0 + tk) * 32 + h * 4];
    float la = lA[(size_t)(b8 + h) * 1024 + n0 + tk];
    float lb = lB[(size_t)(b8 + h) * 1024 + n0 + tk];
    invls[t] = 1.f / (la + lb);
  }
  __syncthreads();

  #pragma unroll
  for (int j = 0; j < 2; ++j) {
    int idx = t * 4 + j * 1024;
    int tk = idx >> 8, o = (idx >> 4) & 15;
    float il = invls[tk * 8 + (o >> 1)];
    xo[idx + 0] = (ra[j].x + rc[j].x) * il;
    xo[idx + 1] = (ra[j].y + rc[j].y) * il;
    xo[idx + 2] = (ra[j].z + rc[j].z) * il;
    xo[idx + 3] = (ra[j].w + rc[j].w) * il;
  }
  if (t < 64) {
    int tk = t >> 3, h = t & 7;
    float il = invls[t];
    xso[tk * 32 + h * 4 + 0] = (sa4.x + sc4.x) * il;
    xso[tk * 32 + h * 4 + 1] = (sa4.y + sc4.y) * il;
    xso[tk * 32 + h * 4 + 2] = (sa4.z + sc4.z) * il;
    xso[tk * 32 + h * 4 + 3] = (sa4.w + sc4.w) * il;
  }
  __syncthreads();

  for (int tk = 0; tk < 8; ++tk) {
    float y = 0.f;
    const float* xb = &xo[tk * 256];
    #pragma unroll
    for (int i = 0; i < 16; ++i) y += wg[i] * xb[i * 16 + a];
    if (pr >= 0) {
      #pragma unroll
      for (int i = 0; i < 16; ++i) y += wp[i] * xb[i * 16 + pr];
    }
    yst[(tk * 16 + og) * 17 + a] = y;
  }
  __syncthreads();

  if (t < 128) {
    int tk = t >> 4, o = t & 15;
    float add = 0.f;
    #pragma unroll
    for (int j = 0; j < 32; ++j) add += wsm[o * 32 + j] * xso[tk * 32 + j];
    yst[(tk * 16 + o) * 17 + 0] += add;
  }
  {
    int o32 = t & 31, tk = t >> 5;
    float ys = 0.f;
    #pragma unroll
    for (int j = 0; j < 32; ++j) ys += wss[o32 * 32 + j] * xso[tk * 32 + j];
    #pragma unroll
    for (int i = 0; i < 16; ++i) ys += wms[o32 * 16 + i] * xo[tk * 256 + i * 16];
    s[(size_t)(tok0 + tk) * 32 + o32] += ys;
  }
  __syncthreads();

  #pragma unroll
  for (int p = 0; p < 8; ++p) {
    int flat = p * 256 + t;
    int tk = flat >> 8, rem = flat & 255, o = rem >> 4, a2 = rem & 15;
    mv[(size_t)tok0 * 256 + flat] += yst[(tk * 16 + o) * 17 + a2];
  }
}

// ---------------- LN + geometric MLP + residual, v2: transposed b128 layouts -------
__global__ void __launch_bounds__(256) k_mlp_res(
    float* __restrict__ mv, float* __restrict__ s,
    const float* __restrict__ w1mv, const float* __restrict__ w1sm,
    const float* __restrict__ w1ms, const float* __restrict__ w1ss,
    const float* __restrict__ w2mv, const float* __restrict__ w2sm,
    const float* __restrict__ w2ms, const float* __restrict__ w2ss)
{
  __shared__ __align__(16) float pool[9120];
  float* xT    = pool;          // [8][16 blade][20 ch]   | alias gstT (xT dead post-B4)
  float* gstT  = pool;
  float* xs    = pool + 2560;   // [8][32]
  float* w1smT = pool + 2816;   // [8][32]
  float* hst   = pool + 3072;   // [8][32 ch][20 blade]
  float* hsst  = pool + 8192;   // [8][64]
  float* shst  = pool + 8704;   // [8][32]
  float* w2smT = pool + 8960;   // [8][16]
  float* redp  = pool + 9088;   // [32]
  // 9120 floats = 36480 B -> 4 blocks/CU

  int t = threadIdx.x;
  int tok0 = blockIdx.x * 8;
  int a = t & 15, og = t >> 4;
  int g = d_GRADE[a], pr = d_PAIR[a];
  int inner_a = ((d_I2M[a] & 1) == 0) ? 1 : 0;
  int tks = t >> 5, o32 = t & 31;

  // GP sign/index packing for output blade k=a
  unsigned long long jpack = 0; unsigned int spack = 0, skipm = 0;
  {
    int mk = d_I2M[a];
    for (int i = 0; i < 16; ++i) {
      int mi = d_I2M[i];
      int mj = mi ^ mk;
      if (mi & mj & 1) { skipm |= 1u << i; continue; }
      int j = d_M2I[mj];
      int sw = 0;
      for (int bb2 = 0; bb2 < 4; ++bb2)
        if (mj & (1 << bb2)) sw += __popc(((unsigned)mi) >> (bb2 + 1));
      jpack |= (unsigned long long)j << (4 * i);
      spack |= (unsigned)(sw & 1) << i;
    }
  }

  // ---- load state into registers (coalesced)
  float mvv[8];
  #pragma unroll
  for (int tk = 0; tk < 8; ++tk)
    mvv[tk] = mv[(size_t)(tok0 + tk) * 256 + t];
  float sold = s[(size_t)(tok0 + tks) * 32 + o32];

  // ---- mv LN: block reduction (8 tokens batched)
  float sq[8];
  #pragma unroll
  for (int tk = 0; tk < 8; ++tk) sq[tk] = inner_a ? mvv[tk] * mvv[tk] : 0.f;
  #pragma unroll
  for (int off = 1; off < 64; off <<= 1) {
    #pragma unroll
    for (int tk = 0; tk < 8; ++tk) sq[tk] += __shfl_xor(sq[tk], off);
  }
  if ((t & 63) == 0) {
    #pragma unroll
    for (int tk = 0; tk < 8; ++tk) redp[(t >> 6) * 8 + tk] = sq[tk];
  }
  __syncthreads();  // B1
  #pragma unroll
  for (int tk = 0; tk < 8; ++tk) {
    float f = redp[tk] + redp[8 + tk] + redp[16 + tk] + redp[24 + tk];
    float inv = rsqrtf(f / 16.f + 1e-6f);
    xT[tk * 320 + a * 20 + og] = mvv[tk] * inv;   // transposed write (2-way banks)
  }
  // s LN (32-lane groups, stays within wave)
  {
    float s2 = sold * sold;
    s2 += __shfl_xor(s2, 1); s2 += __shfl_xor(s2, 2);
    s2 += __shfl_xor(s2, 4); s2 += __shfl_xor(s2, 8); s2 += __shfl_xor(s2, 16);
    float sinv = rsqrtf(s2 / 32.f + 1e-6f);
    xs[tks * 32 + o32] = sold * sinv;
  }
  __syncthreads();  // B2: xT/xs ready

  // w1sm blade-0 terms
  {
    float add = 0.f;
    #pragma unroll
    for (int j = 0; j < 32; ++j) add += w1sm[o32 * 32 + j] * xs[tks * 32 + j];
    w1smT[tks * 32 + o32] = add;
  }
  __syncthreads();  // B3

  // h1 (32 mv channels) — b128 row reads from xT
  {
    float wg1a[16], wp1a[16], wg1b[16], wp1b[16];
    #pragma unroll
    for (int i = 0; i < 16; ++i) {
      wg1a[i] = w1mv[(og)      * 144 + i * 9 + g];
      wg1b[i] = w1mv[(16 + og) * 144 + i * 9 + g];
      wp1a[i] = w1mv[(og)      * 144 + i * 9 + 4 + g];
      wp1b[i] = w1mv[(16 + og) * 144 + i * 9 + 4 + g];
    }
    #pragma unroll
    for (int tk = 0; tk < 8; ++tk) {
      const float* rowa = &xT[tk * 320 + a * 20];
      float4 q0 = *(const float4*)(rowa + 0), q1 = *(const float4*)(rowa + 4);
      float4 q2 = *(const float4*)(rowa + 8), q3 = *(const float4*)(rowa + 12);
      float y0 = q0.x*wg1a[0]+q0.y*wg1a[1]+q0.z*wg1a[2]+q0.w*wg1a[3]
               + q1.x*wg1a[4]+q1.y*wg1a[5]+q1.z*wg1a[6]+q1.w*wg1a[7]
               + q2.x*wg1a[8]+q2.y*wg1a[9]+q2.z*wg1a[10]+q2.w*wg1a[11]
               + q3.x*wg1a[12]+q3.y*wg1a[13]+q3.z*wg1a[14]+q3.w*wg1a[15];
      float y1 = q0.x*wg1b[0]+q0.y*wg1b[1]+q0.z*wg1b[2]+q0.w*wg1b[3]
               + q1.x*wg1b[4]+q1.y*wg1b[5]+q1.z*wg1b[6]+q1.w*wg1b[7]
               + q2.x*wg1b[8]+q2.y*wg1b[9]+q2.z*wg1b[10]+q2.w*wg1b[11]
               + q3.x*wg1b[12]+q3.y*wg1b[13]+q3.z*wg1b[14]+q3.w*wg1b[15];
      if (pr >= 0) {
        const float* rowp = &xT[tk * 320 + pr * 20];
        float4 p0 = *(const float4*)(rowp + 0), p1 = *(const float4*)(rowp + 4);
        float4 p2 = *(const float4*)(rowp + 8), p3 = *(const float4*)(rowp + 12);
        y0 += p0.x*wp1a[0]+p0.y*wp1a[1]+p0.z*wp1a[2]+p0.w*wp1a[3]
            + p1.x*wp1a[4]+p1.y*wp1a[5]+p1.z*wp1a[6]+p1.w*wp1a[7]
            + p2.x*wp1a[8]+p2.y*wp1a[9]+p2.z*wp1a[10]+p2.w*wp1a[11]
            + p3.x*wp1a[12]+p3.y*wp1a[13]+p3.z*wp1a[14]+p3.w*wp1a[15];
        y1 += p0.x*wp1b[0]+p0.y*wp1b[1]+p0.z*wp1b[2]+p0.w*wp1b[3]
            + p1.x*wp1b[4]+p1.y*wp1b[5]+p1.z*wp1b[6]+p1.w*wp1b[7]
            + p2.x*wp1b[8]+p2.y*wp1b[9]+p2.z*wp1b[10]+p2.w*wp1b[11]
            + p3.x*wp1b[12]+p3.y*wp1b[13]+p3.z*wp1b[14]+p3.w*wp1b[15];
      }
      if (a == 0) {
        y0 += w1smT[tk * 32 + og];
        y1 += w1smT[tk * 32 + 16 + og];
      }
      hst[tk * 640 + og * 20 + a] = y0;
      hst[tk * 640 + (16 + og) * 20 + a] = y1;
    }
  }
  // scalar h (64 per token)
  #pragma unroll
  for (int p = 0; p < 2; ++p) {
    int u = p * 256 + t;
    int tk = u >> 6, o64 = u & 63;
    float yy = 0.f;
    #pragma unroll
    for (int j = 0; j < 32; ++j) yy += w1ss[o64 * 32 + j] * xs[tk * 32 + j];
    const float* row0 = &xT[tk * 320];   // blade-0 row (broadcast)
    float4 r0 = *(const float4*)(row0 + 0), r1 = *(const float4*)(row0 + 4);
    float4 r2 = *(const float4*)(row0 + 8), r3 = *(const float4*)(row0 + 12);
    yy += r0.x*w1ms[o64*16+0]+r0.y*w1ms[o64*16+1]+r0.z*w1ms[o64*16+2]+r0.w*w1ms[o64*16+3]
        + r1.x*w1ms[o64*16+4]+r1.y*w1ms[o64*16+5]+r1.z*w1ms[o64*16+6]+r1.w*w1ms[o64*16+7]
        + r2.x*w1ms[o64*16+8]+r2.y*w1ms[o64*16+9]+r2.z*w1ms[o64*16+10]+r2.w*w1ms[o64*16+11]
        + r3.x*w1ms[o64*16+12]+r3.y*w1ms[o64*16+13]+r3.z*w1ms[o64*16+14]+r3.w*w1ms[o64*16+15];
    hsst[tk * 64 + o64] = yy;
  }
  __syncthreads();  // B4: hst/hsst ready (xT dead from here; gstT aliases it)

  // geometric product + gate -> gstT (transposed); scalar gate -> shst
  #pragma unroll
  for (int tk = 0; tk < 8; ++tk) {
    const float* row1 = &hst[tk * 640 + og * 20];   // broadcast within og-group
    float4 q0 = *(const float4*)(row1 + 0), q1 = *(const float4*)(row1 + 4);
    float4 q2 = *(const float4*)(row1 + 8), q3 = *(const float4*)(row1 + 12);
    float r1[16] = {q0.x,q0.y,q0.z,q0.w, q1.x,q1.y,q1.z,q1.w,
                    q2.x,q2.y,q2.z,q2.w, q3.x,q3.y,q3.z,q3.w};
    const float* h2b = &hst[tk * 640 + (16 + og) * 20];
    float gacc = 0.f;
    #pragma unroll
    for (int i = 0; i < 16; ++i) {
      int j = (int)((jpack >> (4 * i)) & 15ull);
      float val = r1[i] * h2b[j];
      float sv = ((spack >> i) & 1) ? -val : val;
      gacc += ((skipm >> i) & 1) ? 0.f : sv;
    }
    float gp0 = __shfl(gacc, (int)(t & 48), 64);
    gstT[tk * 320 + a * 20 + og] = gacc * gelu_tanh(gp0);
  }
  shst[tks * 32 + o32] = hsst[tks * 64 + o32] * gelu_tanh(hsst[tks * 64 + 32 + o32]);
  __syncthreads();  // B5: gstT/shst ready

  // w2sm blade-0 terms
  if (t < 128) {
    int tk = t >> 4, o = t & 15;
    float add = 0.f;
    #pragma unroll
    for (int j = 0; j < 32; ++j) add += w2sm[o * 32 + j] * shst[tk * 32 + j];
    w2smT[tk * 16 + o] = add;
  }
  __syncthreads();  // B6

  // el2 + residual + global writes
  {
    float wg2[16], wp2[16];
    #pragma unroll
    for (int i = 0; i < 16; ++i) {
      wg2[i] = w2mv[og * 144 + i * 9 + g];
      wp2[i] = w2mv[og * 144 + i * 9 + 4 + g];
    }
    #pragma unroll
    for (int tk = 0; tk < 8; ++tk) {
      const float* rowa = &gstT[tk * 320 + a * 20];
      float4 q0 = *(const float4*)(rowa + 0), q1 = *(const float4*)(rowa + 4);
      float4 q2 = *(const float4*)(rowa + 8), q3 = *(const float4*)(rowa + 12);
      float y = q0.x*wg2[0]+q0.y*wg2[1]+q0.z*wg2[2]+q0.w*wg2[3]
              + q1.x*wg2[4]+q1.y*wg2[5]+q1.z*wg2[6]+q1.w*wg2[7]
              + q2.x*wg2[8]+q2.y*wg2[9]+q2.z*wg2[10]+q2.w*wg2[11]
              + q3.x*wg2[12]+q3.y*wg2[13]+q3.z*wg2[14]+q3.w*wg2[15];
      if (pr >= 0) {
        const float* rowp = &gstT[tk * 320 + pr * 20];
        float4 p0 = *(const float4*)(rowp + 0), p1 = *(const float4*)(rowp + 4);
        float4 p2 = *(const float4*)(rowp + 8), p3 = *(const float4*)(rowp + 12);
        y += p0.x*wp2[0]+p0.y*wp2[1]+p0.z*wp2[2]+p0.w*wp2[3]
           + p1.x*wp2[4]+p1.y*wp2[5]+p1.z*wp2[6]+p1.w*wp2[7]
           + p2.x*wp2[8]+p2.y*wp2[9]+p2.z*wp2[10]+p2.w*wp2[11]
           + p3.x*wp2[12]+p3.y*wp2[13]+p3.z*wp2[14]+p3.w*wp2[15];
      }
      if (a == 0) y += w2smT[tk * 16 + og];
      mv[(size_t)(tok0 + tk) * 256 + t] = mvv[tk] + y;
    }
  }
  {
    float ys = 0.f;
    #pragma unroll
    for (int j = 0; j < 32; ++j) ys += w2ss[o32 * 32 + j] * shst[tks * 32 + j];
    const float* row0 = &gstT[tks * 320];   // blade-0 row
    float4 r0 = *(const float4*)(row0 + 0), r1 = *(const float4*)(row0 + 4);
    float4 r2 = *(const float4*)(row0 + 8), r3 = *(const float4*)(row0 + 12);
    ys += r0.x*w2ms[o32*16+0]+r0.y*w2ms[o32*16+1]+r0.z*w2ms[o32*16+2]+r0.w*w2ms[o32*16+3]
        + r1.x*w2ms[o32*16+4]+r1.y*w2ms[o32*16+5]+r1.z*w2ms[o32*16+6]+r1.w*w2ms[o32*16+7]
        + r2.x*w2ms[o32*16+8]+r2.y*w2ms[o32*16+9]+r2.z*w2ms[o32*16+10]+r2.w*w2ms[o32*16+11]
        + r3.x*w2ms[o32*16+12]+r3.y*w2ms[o32*16+13]+r3.z*w2ms[o32*16+14]+r3.w*w2ms[o32*16+15];
    s[(size_t)(tok0 + tks) * 32 + o32] = sold + ys;
  }
}

// ---------------- final projection + mean ----------------
__global__ void __launch_bounds__(256) k_final(
    const float* __restrict__ mv, const float* __restrict__ s,
    const float* __restrict__ wout_mv, const float* __restrict__ wout_sm,
    float* __restrict__ out)
{
  __shared__ float red[256];
  int b = blockIdx.x, t = threadIdx.x;
  float part = 0.f;
  for (int n = t; n < NN; n += 256) {
    const float* mvp = mv + ((size_t)(b * NN + n) * 16) * 16;
    const float* sp = s + (size_t)(b * NN + n) * 32;
    float acc = 0.f;
    #pragma unroll
    for (int i = 0; i < 16; ++i) acc += wout_mv[i * 9] * mvp[i * 16];
    #pragma unroll
    for (int j = 0; j < 32; ++j) acc += wout_sm[j] * sp[j];
    part += acc;
  }
  red[t] = part;
  __syncthreads();
  for (int w = 128; w > 0; w >>= 1) { if (t < w) red[t] += red[t + w]; __syncthreads(); }
  if (t == 0) out[b] = red[0] / (float)NN;
}

extern "C" void kernel_launch(void* const* d_in, const int* in_sizes, int n_in,
                              void* d_out, int out_size, void* d_ws, size_t ws_size,
                              hipStream_t stream) {
  const float* inputs    = (const float*)d_in[0];
  const float* win_mv    = (const float*)d_in[1];
  const float* win_ms    = (const float*)d_in[2];
  const float* win_bs    = (const float*)d_in[3];
  const float* a_qkv_wmv = (const float*)d_in[4];
  const float* a_qkv_wsm = (const float*)d_in[5];
  const float* a_qkv_wms = (const float*)d_in[6];
  const float* a_qkv_wss = (const float*)d_in[7];
  const float* a_out_wmv = (const float*)d_in[8];
  const float* a_out_wsm = (const float*)d_in[9];
  const float* a_out_wms = (const float*)d_in[10];
  const float* a_out_wss = (const float*)d_in[11];
  const float* m1_wmv    = (const float*)d_in[12];
  const float* m1_wsm    = (const float*)d_in[13];
  const float* m1_wms    = (const float*)d_in[14];
  const float* m1_wss    = (const float*)d_in[15];
  const float* m2_wmv    = (const float*)d_in[16];
  const float* m2_wsm    = (const float*)d_in[17];
  const float* m2_wms    = (const float*)d_in[18];
  const float* m2_wss    = (const float*)d_in[19];
  const float* wout_mv   = (const float*)d_in[20];
  const float* wout_sm   = (const float*)d_in[21];
  float* out = (float*)d_out;

  float* ws = (float*)d_ws;
  float* mv    = ws;                    // 2097152 f
  float* s     = mv + 2097152;          // 262144 f
  float* o_mvA = s + 262144;            // A: o_mv + o_s; B follows
  float* lA    = o_mvA + 2 * 2359296;   // 2 x 65536
  ushort_t* q_bf = (ushort_t*)(lA + 2 * 65536);  // 2097152 bf16
  ushort_t* k_bf = q_bf + 2097152;               // 2097152 bf16
  ushort_t* vT   = k_bf + 2097152;               // 3145728 bf16

  int ntok = BB * NN;
  int ntile = ntok / 8;  // 1024
  k_embed<<<ntok, 256, 0, stream>>>(inputs, win_mv, win_ms, win_bs, mv, s);

  for (int l = 0; l < LLAYERS; ++l) {
    k_ln_qkv<<<ntile, 256, 0, stream>>>(mv, s,
        a_qkv_wmv + (size_t)l * 48 * 16 * 9, a_qkv_wsm + (size_t)l * 48 * 32,
        a_qkv_wms + (size_t)l * 96 * 16,     a_qkv_wss + (size_t)l * 96 * 32,
        q_bf, k_bf, vT);
    k_attn<<<2048, 256, 0, stream>>>(q_bf, k_bf, vT, o_mvA, lA);
    k_out_res<<<ntile, 256, 0, stream>>>(o_mvA, lA,
        a_out_wmv + (size_t)l * 16 * 16 * 9, a_out_wsm + (size_t)l * 16 * 32,
        a_out_wms + (size_t)l * 32 * 16,     a_out_wss + (size_t)l * 32 * 32,
        mv, s);
    k_mlp_res<<<ntile, 256, 0, stream>>>(mv, s,
        m1_wmv + (size_t)l * 32 * 16 * 9, m1_wsm + (size_t)l * 32 * 32,
        m1_wms + (size_t)l * 64 * 16,     m1_wss + (size_t)l * 64 * 32,
        m2_wmv + (size_t)l * 16 * 16 * 9, m2_wsm + (size_t)l * 16 * 32,
        m2_wms + (size_t)l * 32 * 16,     m2_wss + (size_t)l * 32 * 32);
  }

  k_final<<<BB, 256, 0, stream>>>(mv, s, wout_mv, wout_sm, out);

  (void)in_sizes; (void)n_in; (void)out_size; (void)ws_size;
}

// Round 10
// 1021.970 us; speedup vs baseline: 1.1115x; 1.1115x over previous
//
#include <hip/hip_runtime.h>
#include <math.h>

#define BB 8
#define NN 1024
#define LLAYERS 8

typedef unsigned short ushort_t;
typedef unsigned int uint_t;
using bf16x8 = __attribute__((ext_vector_type(8))) short;
using f32x4  = __attribute__((ext_vector_type(4))) float;

__constant__ int d_GRADE[16] = {0,1,1,1,1,2,2,2,2,2,2,3,3,3,3,4};
__constant__ int d_PAIR[16]  = {-1,0,-1,-1,-1,2,3,4,-1,-1,-1,8,9,10,-1,14};
__constant__ int d_IB[8] = {0,2,3,4,8,9,10,14};
__constant__ int d_I2M[16] = {0,1,2,4,8,3,5,9,6,10,12,7,11,13,14,15};
__constant__ int d_M2I[16] = {0,1,2,5,3,6,8,11,4,7,9,12,10,13,14,15};

#define QSCALE (0.22360679774997896f * 1.4426950408889634f)

// gelu(x)=0.5x(1+tanh(y)) = x/(1+exp(-2y)), y=0.79788456(x+0.044715x^3)
__device__ __forceinline__ float gelu_tanh(float x) {
  float y = 0.7978845608028654f * (x + 0.044715f * x * x * x);
  float e2 = __builtin_amdgcn_exp2f(y * -2.8853900817779268f);
  return x * __builtin_amdgcn_rcpf(1.0f + e2);
}

__device__ __forceinline__ ushort_t f2b(float f) {
  union { float f; unsigned int u; } x;
  x.f = f;
  unsigned int r = x.u + 0x7fffu + ((x.u >> 16) & 1u);  // RNE
  return (ushort_t)(r >> 16);
}

// ---------------- embed ----------------
__global__ void __launch_bounds__(256) k_embed(
    const float* __restrict__ inp, const float* __restrict__ win_mv,
    const float* __restrict__ win_ms, const float* __restrict__ win_bs,
    float* __restrict__ mv, float* __restrict__ s)
{
  int tok = blockIdx.x, t = threadIdx.x;
  float x = inp[tok * 3 + 0];
  float y = inp[tok * 3 + 1];
  float z = inp[tok * 3 + 2];
  int o = t >> 4, aa = t & 15;
  float ma = (aa == 14) ? 1.f : (aa == 13) ? -x : (aa == 12) ? y : (aa == 11) ? -z : 0.f;
  int g = d_GRADE[aa];
  float val = win_mv[o * 9 + g] * ma;
  int pr = d_PAIR[aa];
  if (pr >= 0) {
    float mp = (pr == 14) ? 1.f : 0.f;
    val += win_mv[o * 9 + 4 + g] * mp;
  }
  mv[(size_t)tok * 256 + t] = val;
  if (t < 32) s[(size_t)tok * 32 + t] = win_bs[t];
  (void)win_ms;
}

// ---------------- LN + QKV projection, 8-token tile ----------------
__global__ void __launch_bounds__(256) k_ln_qkv(
    const float* __restrict__ mv, const float* __restrict__ s,
    const float* __restrict__ wmv, const float* __restrict__ wsm,
    const float* __restrict__ wms, const float* __restrict__ wss,
    ushort_t* __restrict__ q_bf, ushort_t* __restrict__ k_bf, ushort_t* __restrict__ vT)
{
  __shared__ float pool[9600];
  float* xmv = pool;           // [8][256]
  float* xs  = pool + 2048;    // [8][32]
  float* yst = pool + 2304;    // [8][48] rows, stride 17
  float* sst = pool + 8832;    // [8][96]

  int t = threadIdx.x;
  int tok0 = blockIdx.x * 8;
  int b = tok0 >> 10, n0 = tok0 & 1023;
  int a = t & 15, og = t >> 4;
  int g = d_GRADE[a], pr = d_PAIR[a];

  float wgq[16], wpq[16], wgk[16], wpk[16], wgv[16], wpv[16];
  #pragma unroll
  for (int i = 0; i < 16; ++i) {
    wgq[i] = wmv[(og)      * 144 + i * 9 + g];
    wgk[i] = wmv[(16 + og) * 144 + i * 9 + g];
    wgv[i] = wmv[(32 + og) * 144 + i * 9 + g];
    wpq[i] = wmv[(og)      * 144 + i * 9 + 4 + g];
    wpk[i] = wmv[(16 + og) * 144 + i * 9 + 4 + g];
    wpv[i] = wmv[(32 + og) * 144 + i * 9 + 4 + g];
  }

  #pragma unroll
  for (int j = 0; j < 2; ++j)
    *(float4*)&xmv[t * 4 + j * 1024] = *(const float4*)&mv[(size_t)tok0 * 256 + t * 4 + j * 1024];
  if (t < 64)
    *(float4*)&xs[t * 4] = *(const float4*)&s[(size_t)tok0 * 32 + t * 4];
  __syncthreads();

  if (t < 128) {
    int tk = t >> 4, ch = t & 15;
    float* xp = &xmv[tk * 256 + ch * 16];
    float4 v0 = *(float4*)&xp[0], v1 = *(float4*)&xp[4];
    float4 v2 = *(float4*)&xp[8], v3 = *(float4*)&xp[12];
    float ss = v0.x*v0.x + v0.z*v0.z + v0.w*v0.w + v1.x*v1.x
             + v2.x*v2.x + v2.y*v2.y + v2.z*v2.z + v3.z*v3.z;
    ss += __shfl_xor(ss, 1); ss += __shfl_xor(ss, 2);
    ss += __shfl_xor(ss, 4); ss += __shfl_xor(ss, 8);
    float inv = rsqrtf(ss / 16.f + 1e-6f);
    v0.x*=inv; v0.y*=inv; v0.z*=inv; v0.w*=inv;
    v1.x*=inv; v1.y*=inv; v1.z*=inv; v1.w*=inv;
    v2.x*=inv; v2.y*=inv; v2.z*=inv; v2.w*=inv;
    v3.x*=inv; v3.y*=inv; v3.z*=inv; v3.w*=inv;
    *(float4*)&xp[0] = v0; *(float4*)&xp[4] = v1;
    *(float4*)&xp[8] = v2; *(float4*)&xp[12] = v3;
    float s0 = xs[tk * 32 + ch * 2], s1 = xs[tk * 32 + ch * 2 + 1];
    float s2 = s0 * s0 + s1 * s1;
    s2 += __shfl_xor(s2, 1); s2 += __shfl_xor(s2, 2);
    s2 += __shfl_xor(s2, 4); s2 += __shfl_xor(s2, 8);
    float sinv = rsqrtf(s2 / 32.f + 1e-6f);
    xs[tk * 32 + ch * 2] = s0 * sinv;
    xs[tk * 32 + ch * 2 + 1] = s1 * sinv;
  }
  __syncthreads();

  for (int tk = 0; tk < 8; ++tk) {
    float y0 = 0.f, y1 = 0.f, y2 = 0.f;
    const float* xb = &xmv[tk * 256];
    #pragma unroll
    for (int i = 0; i < 16; ++i) {
      float xa_ = xb[i * 16 + a];
      y0 += wgq[i] * xa_; y1 += wgk[i] * xa_; y2 += wgv[i] * xa_;
    }
    if (pr >= 0) {
      #pragma unroll
      for (int i = 0; i < 16; ++i) {
        float xp_ = xb[i * 16 + pr];
        y0 += wpq[i] * xp_; y1 += wpk[i] * xp_; y2 += wpv[i] * xp_;
      }
    }
    yst[(tk * 48 + og) * 17 + a] = y0;
    yst[(tk * 48 + 16 + og) * 17 + a] = y1;
    yst[(tk * 48 + 32 + og) * 17 + a] = y2;
  }
  __syncthreads();

  for (int u = t; u < 384; u += 256) {
    int tk = u / 48, o = u % 48;
    float add = 0.f;
    #pragma unroll
    for (int j = 0; j < 32; ++j) add += wsm[o * 32 + j] * xs[tk * 32 + j];
    yst[(tk * 48 + o) * 17 + 0] += add;
  }
  for (int u = t; u < 768; u += 256) {
    int tk = u / 96, o96 = u % 96;
    float yy = 0.f;
    #pragma unroll
    for (int j = 0; j < 32; ++j) yy += wss[o96 * 32 + j] * xs[tk * 32 + j];
    #pragma unroll
    for (int i = 0; i < 16; ++i) yy += wms[o96 * 16 + i] * xmv[tk * 256 + i * 16];
    sst[tk * 96 + o96] = yy;
  }
  __syncthreads();

  if (t < 128) {
    int isK = t >> 6;
    int r = t & 63;
    int tk = r >> 3, h = r & 7;
    float scale = isK ? 1.f : QSCALE;
    const float* base = &yst[(tk * 48 + isK * 16) * 17];
    ushort_t tmp[32];
    #pragma unroll
    for (int j = 0; j < 8; ++j) {
      int blade = d_IB[j];
      tmp[j]     = f2b(base[(2 * h)     * 17 + blade] * scale);
      tmp[8 + j] = f2b(base[(2 * h + 1) * 17 + blade] * scale);
    }
    #pragma unroll
    for (int d = 0; d < 4; ++d)
      tmp[16 + d] = f2b(sst[tk * 96 + isK * 32 + h * 4 + d] * scale);
    #pragma unroll
    for (int j2 = 20; j2 < 32; ++j2) tmp[j2] = 0;
    uint_t out[16];
    #pragma unroll
    for (int j3 = 0; j3 < 16; ++j3)
      out[j3] = (uint_t)tmp[2 * j3] | ((uint_t)tmp[2 * j3 + 1] << 16);
    ushort_t* dst = (isK ? k_bf : q_bf) + ((size_t)(b * 8 + h) * 1024 + n0 + tk) * 32;
    *(uint4*)(dst +  0) = make_uint4(out[0],  out[1],  out[2],  out[3]);
    *(uint4*)(dst +  8) = make_uint4(out[4],  out[5],  out[6],  out[7]);
    *(uint4*)(dst + 16) = make_uint4(out[8],  out[9],  out[10], out[11]);
    *(uint4*)(dst + 24) = make_uint4(out[12], out[13], out[14], out[15]);
  }
  {
    int h = t >> 5, dim = t & 31;
    int ch = 2 * h + (dim >> 4), blade = dim & 15;
    uint_t ov[4];
    #pragma unroll
    for (int tk = 0; tk < 8; ++tk) {
      ushort_t bv = f2b(yst[(tk * 48 + 32 + ch) * 17 + blade]);
      if (tk & 1) ov[tk >> 1] |= ((uint_t)bv) << 16; else ov[tk >> 1] = bv;
    }
    ushort_t* dst = vT + ((size_t)(b * 8 + h) * 48 + dim) * 1024 + n0;
    *(uint4*)dst = make_uint4(ov[0], ov[1], ov[2], ov[3]);
  }
  if (t < 32) {
    int h = t >> 2, d = t & 3;
    uint_t ov[4];
    #pragma unroll
    for (int tk = 0; tk < 8; ++tk) {
      ushort_t bv = f2b(sst[tk * 96 + 64 + h * 4 + d]);
      if (tk & 1) ov[tk >> 1] |= ((uint_t)bv) << 16; else ov[tk >> 1] = bv;
    }
    ushort_t* dst = vT + ((size_t)(b * 8 + h) * 48 + 32 + d) * 1024 + n0;
    *(uint4*)dst = make_uint4(ov[0], ov[1], ov[2], ov[3]);
  }
  if (t < 8) {
    ushort_t* dst = vT + ((size_t)(b * 8 + t) * 48 + 36) * 1024 + n0;
    *(uint4*)dst = make_uint4(0x3F803F80u, 0x3F803F80u, 0x3F803F80u, 0x3F803F80u);
  }
}

// ---------------- attention: bf16 MFMA, no-max softmax, LDS-staged K/V ------------
#define OPART_STRIDE 2359296
#define LPART_STRIDE 65536
__global__ void __launch_bounds__(256) k_attn(
    const ushort_t* __restrict__ q_bf, const ushort_t* __restrict__ k_bf,
    const ushort_t* __restrict__ vT, float* __restrict__ o_mvA, float* __restrict__ lA)
{
  __shared__ __align__(16) ushort_t kst[64 * 40];
  __shared__ __align__(16) ushort_t vst[48 * 72];
  __shared__ __align__(16) ushort_t plds[4][1280];
  int bx = blockIdx.x;
  int bh = bx & 63, qg = bx >> 6;
  int qb = qg & 15, kg = qg >> 4;
  int b = bh >> 3, h = bh & 7;
  int t = threadIdx.x;
  int w = t >> 6, lane = t & 63;
  int quad = lane >> 4, col = lane & 15;
  int q16 = qb * 64 + w * 16;
  size_t hb = (size_t)bh * 1024;
  ushort_t* myp = &plds[w][0];

  float* o_mvp = o_mvA + (size_t)kg * OPART_STRIDE;
  float* o_sp  = o_mvp + 2097152;
  float* l_p   = lA + (size_t)kg * LPART_STRIDE;

  bf16x8 qfrag = *(const bf16x8*)(q_bf + (hb + q16 + col) * 32 + quad * 8);

  f32x4 ot0 = {0.f,0.f,0.f,0.f}, ot1 = {0.f,0.f,0.f,0.f}, ot2 = {0.f,0.f,0.f,0.f};

  const ushort_t* kbase = k_bf + hb * 32;
  const ushort_t* vbase = vT + (size_t)bh * 48 * 1024;
  int k0 = kg * 512;

  int skey = t >> 2, sc4 = t & 3;
  for (int kt = 0; kt < 8; ++kt) {
    int kb = k0 + kt * 64;
    __syncthreads();
    *(uint4*)&kst[skey * 40 + sc4 * 8] =
        *(const uint4*)(kbase + (size_t)(kb + skey) * 32 + sc4 * 8);
    for (int u = t; u < 296; u += 256) {
      int row = u >> 3, c8 = u & 7;
      *(uint4*)&vst[row * 72 + c8 * 8] =
          *(const uint4*)(vbase + (size_t)row * 1024 + kb + c8 * 8);
    }
    __syncthreads();

    bf16x8 sk0 = *(const bf16x8*)&kst[(     col) * 40 + quad * 8];
    bf16x8 sk1 = *(const bf16x8*)&kst[(16 + col) * 40 + quad * 8];
    bf16x8 sk2 = *(const bf16x8*)&kst[(32 + col) * 40 + quad * 8];
    bf16x8 sk3 = *(const bf16x8*)&kst[(48 + col) * 40 + quad * 8];
    bf16x8 va0 = *(const bf16x8*)&vst[(     col) * 72 + quad * 8];
    bf16x8 va1 = *(const bf16x8*)&vst[(16 + col) * 72 + quad * 8];
    bf16x8 va2 = *(const bf16x8*)&vst[(32 + col) * 72 + quad * 8];
    bf16x8 vb0 = *(const bf16x8*)&vst[(     col) * 72 + 32 + quad * 8];
    bf16x8 vb1 = *(const bf16x8*)&vst[(16 + col) * 72 + 32 + quad * 8];
    bf16x8 vb2 = *(const bf16x8*)&vst[(32 + col) * 72 + 32 + quad * 8];
    f32x4 zero = {0.f,0.f,0.f,0.f};
    f32x4 sa0 = __builtin_amdgcn_mfma_f32_16x16x32_bf16(sk0, qfrag, zero, 0, 0, 0);
    f32x4 sa1 = __builtin_amdgcn_mfma_f32_16x16x32_bf16(sk1, qfrag, zero, 0, 0, 0);
    f32x4 sb0 = __builtin_amdgcn_mfma_f32_16x16x32_bf16(sk2, qfrag, zero, 0, 0, 0);
    f32x4 sb1 = __builtin_amdgcn_mfma_f32_16x16x32_bf16(sk3, qfrag, zero, 0, 0, 0);

    union { float f; uint_t u; } e0, e1, e2, e3;
    e0.f = __builtin_amdgcn_exp2f(sa0[0]); e1.f = __builtin_amdgcn_exp2f(sa0[1]);
    e2.f = __builtin_amdgcn_exp2f(sa0[2]); e3.f = __builtin_amdgcn_exp2f(sa0[3]);
    uint_t a0 = __builtin_amdgcn_perm(e1.u, e0.u, 0x07060302u);
    uint_t a1 = __builtin_amdgcn_perm(e3.u, e2.u, 0x07060302u);
    e0.f = __builtin_amdgcn_exp2f(sa1[0]); e1.f = __builtin_amdgcn_exp2f(sa1[1]);
    e2.f = __builtin_amdgcn_exp2f(sa1[2]); e3.f = __builtin_amdgcn_exp2f(sa1[3]);
    uint_t a2 = __builtin_amdgcn_perm(e1.u, e0.u, 0x07060302u);
    uint_t a3 = __builtin_amdgcn_perm(e3.u, e2.u, 0x07060302u);
    e0.f = __builtin_amdgcn_exp2f(sb0[0]); e1.f = __builtin_amdgcn_exp2f(sb0[1]);
    e2.f = __builtin_amdgcn_exp2f(sb0[2]); e3.f = __builtin_amdgcn_exp2f(sb0[3]);
    uint_t b0 = __builtin_amdgcn_perm(e1.u, e0.u, 0x07060302u);
    uint_t b1 = __builtin_amdgcn_perm(e3.u, e2.u, 0x07060302u);
    e0.f = __builtin_amdgcn_exp2f(sb1[0]); e1.f = __builtin_amdgcn_exp2f(sb1[1]);
    e2.f = __builtin_amdgcn_exp2f(sb1[2]); e3.f = __builtin_amdgcn_exp2f(sb1[3]);
    uint_t b2 = __builtin_amdgcn_perm(e1.u, e0.u, 0x07060302u);
    uint_t b3 = __builtin_amdgcn_perm(e3.u, e2.u, 0x07060302u);

    *(uint2*)(myp + col * 40 + quad * 4)            = make_uint2(a0, a1);
    *(uint2*)(myp + col * 40 + 16 + quad * 4)       = make_uint2(a2, a3);
    *(uint2*)(myp + 640 + col * 40 + quad * 4)      = make_uint2(b0, b1);
    *(uint2*)(myp + 640 + col * 40 + 16 + quad * 4) = make_uint2(b2, b3);
    __builtin_amdgcn_wave_barrier();
    bf16x8 pfa = *(const bf16x8*)(myp + col * 40 + quad * 8);
    bf16x8 pfb = *(const bf16x8*)(myp + 640 + col * 40 + quad * 8);
    __builtin_amdgcn_wave_barrier();
    ot0 = __builtin_amdgcn_mfma_f32_16x16x32_bf16(va0, pfa, ot0, 0, 0, 0);
    ot1 = __builtin_amdgcn_mfma_f32_16x16x32_bf16(va1, pfa, ot1, 0, 0, 0);
    ot2 = __builtin_amdgcn_mfma_f32_16x16x32_bf16(va2, pfa, ot2, 0, 0, 0);
    ot0 = __builtin_amdgcn_mfma_f32_16x16x32_bf16(vb0, pfb, ot0, 0, 0, 0);
    ot1 = __builtin_amdgcn_mfma_f32_16x16x32_bf16(vb1, pfb, ot1, 0, 0, 0);
    ot2 = __builtin_amdgcn_mfma_f32_16x16x32_bf16(vb2, pfb, ot2, 0, 0, 0);
  }

  int tok = b * NN + q16 + col;
  float* op0 = o_mvp + (size_t)tok * 256 + (2 * h) * 16 + quad * 4;
  op0[0] = ot0[0]; op0[1] = ot0[1]; op0[2] = ot0[2]; op0[3] = ot0[3];
  float* op1 = o_mvp + (size_t)tok * 256 + (2 * h + 1) * 16 + quad * 4;
  op1[0] = ot1[0]; op1[1] = ot1[1]; op1[2] = ot1[2]; op1[3] = ot1[3];
  if (quad == 0) {
    float* osp = o_sp + (size_t)tok * 32 + h * 4;
    osp[0] = ot2[0]; osp[1] = ot2[1]; osp[2] = ot2[2]; osp[3] = ot2[3];
  }
  if (quad == 1) l_p[hb + q16 + col] = ot2[0];
}

// ---------------- attention combine + out-proj + residual, 8-token tile -----------
__global__ void __launch_bounds__(256) k_out_res(
    const float* __restrict__ o_mvA, const float* __restrict__ lA,
    const float* __restrict__ wmv, const float* __restrict__ wsm,
    const float* __restrict__ wms, const float* __restrict__ wss,
    float* __restrict__ mv, float* __restrict__ s)
{
  __shared__ float pool[4544];
  float* xo    = pool;          // [8][256]
  float* xso   = pool + 2048;   // [8][32]
  float* yst   = pool + 2304;   // [8][16] rows, stride 17
  float* invls = pool + 4480;   // [8][8]

  const float* o_sA  = o_mvA + 2097152;
  const float* o_mvB = o_mvA + OPART_STRIDE;
  const float* o_sB  = o_mvB + 2097152;
  const float* lB    = lA + LPART_STRIDE;

  int t = threadIdx.x;
  int tok0 = blockIdx.x * 8;
  int b8 = (tok0 >> 10) * 8, n0 = tok0 & 1023;
  int a = t & 15, og = t >> 4;
  int g = d_GRADE[a], pr = d_PAIR[a];

  float wg[16], wp[16];
  #pragma unroll
  for (int i = 0; i < 16; ++i) {
    wg[i] = wmv[og * 144 + i * 9 + g];
    wp[i] = wmv[og * 144 + i * 9 + 4 + g];
  }

  float4 ra[2], rc[2];
  #pragma unroll
  for (int j = 0; j < 2; ++j) {
    ra[j] = *(const float4*)&o_mvA[(size_t)tok0 * 256 + t * 4 + j * 1024];
    rc[j] = *(const float4*)&o_mvB[(size_t)tok0 * 256 + t * 4 + j * 1024];
  }
  float4 sa4 = {0,0,0,0}, sc4 = {0,0,0,0};
  if (t < 64) {
    int tk = t >> 3, h = t & 7;
    sa4 = *(const float4*)&o_sA[(size_t)(tok0 + tk) * 32 + h * 4];
    sc4 = *(const float4*)&o_sB[(size_t)(tok0 + tk) * 32 + h * 4];
    float la = lA[(size_t)(b8 + h) * 1024 + n0 + tk];
    float lb = lB[(size_t)(b8 + h) * 1024 + n0 + tk];
    invls[t] = 1.f / (la + lb);
  }
  __syncthreads();

  #pragma unroll
  for (int j = 0; j < 2; ++j) {
    int idx = t * 4 + j * 1024;
    int tk = idx >> 8, o = (idx >> 4) & 15;
    float il = invls[tk * 8 + (o >> 1)];
    xo[idx + 0] = (ra[j].x + rc[j].x) * il;
    xo[idx + 1] = (ra[j].y + rc[j].y) * il;
    xo[idx + 2] = (ra[j].z + rc[j].z) * il;
    xo[idx + 3] = (ra[j].w + rc[j].w) * il;
  }
  if (t < 64) {
    int tk = t >> 3, h = t & 7;
    float il = invls[t];
    xso[tk * 32 + h * 4 + 0] = (sa4.x + sc4.x) * il;
    xso[tk * 32 + h * 4 + 1] = (sa4.y + sc4.y) * il;
    xso[tk * 32 + h * 4 + 2] = (sa4.z + sc4.z) * il;
    xso[tk * 32 + h * 4 + 3] = (sa4.w + sc4.w) * il;
  }
  __syncthreads();

  for (int tk = 0; tk < 8; ++tk) {
    float y = 0.f;
    const float* xb = &xo[tk * 256];
    #pragma unroll
    for (int i = 0; i < 16; ++i) y += wg[i] * xb[i * 16 + a];
    if (pr >= 0) {
      #pragma unroll
      for (int i = 0; i < 16; ++i) y += wp[i] * xb[i * 16 + pr];
    }
    yst[(tk * 16 + og) * 17 + a] = y;
  }
  __syncthreads();

  if (t < 128) {
    int tk = t >> 4, o = t & 15;
    float add = 0.f;
    #pragma unroll
    for (int j = 0; j < 32; ++j) add += wsm[o * 32 + j] * xso[tk * 32 + j];
    yst[(tk * 16 + o) * 17 + 0] += add;
  }
  {
    int o32 = t & 31, tk = t >> 5;
    float ys = 0.f;
    #pragma unroll
    for (int j = 0; j < 32; ++j) ys += wss[o32 * 32 + j] * xso[tk * 32 + j];
    #pragma unroll
    for (int i = 0; i < 16; ++i) ys += wms[o32 * 16 + i] * xo[tk * 256 + i * 16];
    s[(size_t)(tok0 + tk) * 32 + o32] += ys;
  }
  __syncthreads();

  #pragma unroll
  for (int p = 0; p < 8; ++p) {
    int flat = p * 256 + t;
    int tk = flat >> 8, rem = flat & 255, o = rem >> 4, a2 = rem & 15;
    mv[(size_t)tok0 * 256 + flat] += yst[(tk * 16 + o) * 17 + a2];
  }
}

// ---------------- LN + geometric MLP + residual, 8-token tile (R7 version) --------
__global__ void __launch_bounds__(256) k_mlp_res(
    float* __restrict__ mv, float* __restrict__ s,
    const float* __restrict__ w1mv, const float* __restrict__ w1sm,
    const float* __restrict__ w1ms, const float* __restrict__ w1ss,
    const float* __restrict__ w2mv, const float* __restrict__ w2sm,
    const float* __restrict__ w2ms, const float* __restrict__ w2ss)
{
  __shared__ float pool[9600];
  float* xmv  = pool;           // [8][256]
  float* xs   = pool + 2048;    // [8][32]
  float* hst  = pool + 2304;    // [8][32] rows, stride 17
  float* y2st = pool + 2304;    // alias of hst (dead when reused)
  float* hsst = pool + 6656;    // [8][64]
  float* gst  = pool + 7168;    // [8][16] rows, stride 17
  float* shst = pool + 9344;    // [8][32]

  int t = threadIdx.x;
  int tok0 = blockIdx.x * 8;
  int a = t & 15, og = t >> 4;
  int g = d_GRADE[a], pr = d_PAIR[a];

  unsigned long long jpack = 0; unsigned int spack = 0, skipm = 0;
  {
    int mk = d_I2M[a];
    for (int i = 0; i < 16; ++i) {
      int mi = d_I2M[i];
      int mj = mi ^ mk;
      if (mi & mj & 1) { skipm |= 1u << i; continue; }
      int j = d_M2I[mj];
      int sw = 0;
      for (int bb2 = 0; bb2 < 4; ++bb2)
        if (mj & (1 << bb2)) sw += __popc(((unsigned)mi) >> (bb2 + 1));
      jpack |= (unsigned long long)j << (4 * i);
      spack |= (unsigned)(sw & 1) << i;
    }
  }

  float wg1a[16], wp1a[16], wg1b[16], wp1b[16];
  #pragma unroll
  for (int i = 0; i < 16; ++i) {
    wg1a[i] = w1mv[(og)      * 144 + i * 9 + g];
    wg1b[i] = w1mv[(16 + og) * 144 + i * 9 + g];
    wp1a[i] = w1mv[(og)      * 144 + i * 9 + 4 + g];
    wp1b[i] = w1mv[(16 + og) * 144 + i * 9 + 4 + g];
  }

  #pragma unroll
  for (int j = 0; j < 2; ++j)
    *(float4*)&xmv[t * 4 + j * 1024] = *(const float4*)&mv[(size_t)tok0 * 256 + t * 4 + j * 1024];
  if (t < 64)
    *(float4*)&xs[t * 4] = *(const float4*)&s[(size_t)tok0 * 32 + t * 4];
  __syncthreads();

  if (t < 128) {
    int tk = t >> 4, ch = t & 15;
    float* xp = &xmv[tk * 256 + ch * 16];
    float4 v0 = *(float4*)&xp[0], v1 = *(float4*)&xp[4];
    float4 v2 = *(float4*)&xp[8], v3 = *(float4*)&xp[12];
    float ss = v0.x*v0.x + v0.z*v0.z + v0.w*v0.w + v1.x*v1.x
             + v2.x*v2.x + v2.y*v2.y + v2.z*v2.z + v3.z*v3.z;
    ss += __shfl_xor(ss, 1); ss += __shfl_xor(ss, 2);
    ss += __shfl_xor(ss, 4); ss += __shfl_xor(ss, 8);
    float inv = rsqrtf(ss / 16.f + 1e-6f);
    v0.x*=inv; v0.y*=inv; v0.z*=inv; v0.w*=inv;
    v1.x*=inv; v1.y*=inv; v1.z*=inv; v1.w*=inv;
    v2.x*=inv; v2.y*=inv; v2.z*=inv; v2.w*=inv;
    v3.x*=inv; v3.y*=inv; v3.z*=inv; v3.w*=inv;
    *(float4*)&xp[0] = v0; *(float4*)&xp[4] = v1;
    *(float4*)&xp[8] = v2; *(float4*)&xp[12] = v3;
    float s0 = xs[tk * 32 + ch * 2], s1 = xs[tk * 32 + ch * 2 + 1];
    float s2 = s0 * s0 + s1 * s1;
    s2 += __shfl_xor(s2, 1); s2 += __shfl_xor(s2, 2);
    s2 += __shfl_xor(s2, 4); s2 += __shfl_xor(s2, 8);
    float sinv = rsqrtf(s2 / 32.f + 1e-6f);
    xs[tk * 32 + ch * 2] = s0 * sinv;
    xs[tk * 32 + ch * 2 + 1] = s1 * sinv;
  }
  __syncthreads();

  for (int tk = 0; tk < 8; ++tk) {
    float y0 = 0.f, y1 = 0.f;
    const float* xb = &xmv[tk * 256];
    #pragma unroll
    for (int i = 0; i < 16; ++i) {
      float xa_ = xb[i * 16 + a];
      y0 += wg1a[i] * xa_; y1 += wg1b[i] * xa_;
    }
    if (pr >= 0) {
      #pragma unroll
      for (int i = 0; i < 16; ++i) {
        float xp_ = xb[i * 16 + pr];
        y0 += wp1a[i] * xp_; y1 += wp1b[i] * xp_;
      }
    }
    hst[(tk * 32 + og) * 17 + a] = y0;
    hst[(tk * 32 + 16 + og) * 17 + a] = y1;
  }
  for (int u = t; u < 512; u += 256) {
    int tk = u >> 6, o64 = u & 63;
    float yy = 0.f;
    #pragma unroll
    for (int j = 0; j < 32; ++j) yy += w1ss[o64 * 32 + j] * xs[tk * 32 + j];
    #pragma unroll
    for (int i = 0; i < 16; ++i) yy += w1ms[o64 * 16 + i] * xmv[tk * 256 + i * 16];
    hsst[tk * 64 + o64] = yy;
  }
  __syncthreads();

  {
    int tk = t >> 5, o = t & 31;
    float add = 0.f;
    #pragma unroll
    for (int j = 0; j < 32; ++j) add += w1sm[o * 32 + j] * xs[tk * 32 + j];
    hst[(tk * 32 + o) * 17 + 0] += add;
  }
  __syncthreads();

  for (int tk = 0; tk < 8; ++tk) {
    const float* h1b = &hst[(tk * 32 + og) * 17];
    const float* h2b = &hst[(tk * 32 + 16 + og) * 17];
    float gacc = 0.f;
    #pragma unroll
    for (int i = 0; i < 16; ++i) {
      int j = (int)((jpack >> (4 * i)) & 15ull);
      float val = h1b[i] * h2b[j];
      float sv = ((spack >> i) & 1) ? -val : val;
      gacc += ((skipm >> i) & 1) ? 0.f : sv;
    }
    float gp0 = __shfl(gacc, (int)(t & 48), 64);
    gst[(tk * 16 + og) * 17 + a] = gacc * gelu_tanh(gp0);
  }
  {
    int tk = t >> 5, o32 = t & 31;
    shst[tk * 32 + o32] = hsst[tk * 64 + o32] * gelu_tanh(hsst[tk * 64 + 32 + o32]);
  }
  __syncthreads();

  {
    float wg2[16], wp2[16];
    #pragma unroll
    for (int i = 0; i < 16; ++i) {
      wg2[i] = w2mv[og * 144 + i * 9 + g];
      wp2[i] = w2mv[og * 144 + i * 9 + 4 + g];
    }
    for (int tk = 0; tk < 8; ++tk) {
      float y = 0.f;
      #pragma unroll
      for (int i = 0; i < 16; ++i) y += wg2[i] * gst[(tk * 16 + i) * 17 + a];
      if (pr >= 0) {
        #pragma unroll
        for (int i = 0; i < 16; ++i) y += wp2[i] * gst[(tk * 16 + i) * 17 + pr];
      }
      y2st[(tk * 16 + og) * 17 + a] = y;
    }
  }
  __syncthreads();

  if (t < 128) {
    int tk = t >> 4, o = t & 15;
    float add = 0.f;
    #pragma unroll
    for (int j = 0; j < 32; ++j) add += w2sm[o * 32 + j] * shst[tk * 32 + j];
    y2st[(tk * 16 + o) * 17 + 0] += add;
  }
  {
    int tk = t >> 5, o32 = t & 31;
    float ys = 0.f;
    #pragma unroll
    for (int j = 0; j < 32; ++j) ys += w2ss[o32 * 32 + j] * shst[tk * 32 + j];
    #pragma unroll
    for (int i = 0; i < 16; ++i) ys += w2ms[o32 * 16 + i] * gst[(tk * 16 + i) * 17 + 0];
    s[(size_t)(tok0 + tk) * 32 + o32] += ys;
  }
  __syncthreads();

  #pragma unroll
  for (int p = 0; p < 8; ++p) {
    int flat = p * 256 + t;
    int tk = flat >> 8, rem = flat & 255, o = rem >> 4, a2 = rem & 15;
    mv[(size_t)tok0 * 256 + flat] += y2st[(tk * 16 + o) * 17 + a2];
  }
}

// ---------------- final projection + mean ----------------
__global__ void __launch_bounds__(256) k_final(
    const float* __restrict__ mv, const float* __restrict__ s,
    const float* __restrict__ wout_mv, const float* __restrict__ wout_sm,
    float* __restrict__ out)
{
  __shared__ float red[256];
  int b = blockIdx.x, t = threadIdx.x;
  float part = 0.f;
  for (int n = t; n < NN; n += 256) {
    const float* mvp = mv + ((size_t)(b * NN + n) * 16) * 16;
    const float* sp = s + (size_t)(b * NN + n) * 32;
    float acc = 0.f;
    #pragma unroll
    for (int i = 0; i < 16; ++i) acc += wout_mv[i * 9] * mvp[i * 16];
    #pragma unroll
    for (int j = 0; j < 32; ++j) acc += wout_sm[j] * sp[j];
    part += acc;
  }
  red[t] = part;
  __syncthreads();
  for (int w = 128; w > 0; w >>= 1) { if (t < w) red[t] += red[t + w]; __syncthreads(); }
  if (t == 0) out[b] = red[0] / (float)NN;
}

extern "C" void kernel_launch(void* const* d_in, const int* in_sizes, int n_in,
                              void* d_out, int out_size, void* d_ws, size_t ws_size,
                              hipStream_t stream) {
  const float* inputs    = (const float*)d_in[0];
  const float* win_mv    = (const float*)d_in[1];
  const float* win_ms    = (const float*)d_in[2];
  const float* win_bs    = (const float*)d_in[3];
  const float* a_qkv_wmv = (const float*)d_in[4];
  const float* a_qkv_wsm = (const float*)d_in[5];
  const float* a_qkv_wms = (const float*)d_in[6];
  const float* a_qkv_wss = (const float*)d_in[7];
  const float* a_out_wmv = (const float*)d_in[8];
  const float* a_out_wsm = (const float*)d_in[9];
  const float* a_out_wms = (const float*)d_in[10];
  const float* a_out_wss = (const float*)d_in[11];
  const float* m1_wmv    = (const float*)d_in[12];
  const float* m1_wsm    = (const float*)d_in[13];
  const float* m1_wms    = (const float*)d_in[14];
  const float* m1_wss    = (const float*)d_in[15];
  const float* m2_wmv    = (const float*)d_in[16];
  const float* m2_wsm    = (const float*)d_in[17];
  const float* m2_wms    = (const float*)d_in[18];
  const float* m2_wss    = (const float*)d_in[19];
  const float* wout_mv   = (const float*)d_in[20];
  const float* wout_sm   = (const float*)d_in[21];
  float* out = (float*)d_out;

  float* ws = (float*)d_ws;
  float* mv    = ws;                    // 2097152 f
  float* s     = mv + 2097152;          // 262144 f
  float* o_mvA = s + 262144;            // A: o_mv + o_s; B follows
  float* lA    = o_mvA + 2 * 2359296;   // 2 x 65536
  ushort_t* q_bf = (ushort_t*)(lA + 2 * 65536);  // 2097152 bf16
  ushort_t* k_bf = q_bf + 2097152;               // 2097152 bf16
  ushort_t* vT   = k_bf + 2097152;               // 3145728 bf16

  int ntok = BB * NN;
  int ntile = ntok / 8;  // 1024
  k_embed<<<ntok, 256, 0, stream>>>(inputs, win_mv, win_ms, win_bs, mv, s);

  for (int l = 0; l < LLAYERS; ++l) {
    k_ln_qkv<<<ntile, 256, 0, stream>>>(mv, s,
        a_qkv_wmv + (size_t)l * 48 * 16 * 9, a_qkv_wsm + (size_t)l * 48 * 32,
        a_qkv_wms + (size_t)l * 96 * 16,     a_qkv_wss + (size_t)l * 96 * 32,
        q_bf, k_bf, vT);
    k_attn<<<2048, 256, 0, stream>>>(q_bf, k_bf, vT, o_mvA, lA);
    k_out_res<<<ntile, 256, 0, stream>>>(o_mvA, lA,
        a_out_wmv + (size_t)l * 16 * 16 * 9, a_out_wsm + (size_t)l * 16 * 32,
        a_out_wms + (size_t)l * 32 * 16,     a_out_wss + (size_t)l * 32 * 32,
        mv, s);
    k_mlp_res<<<ntile, 256, 0, stream>>>(mv, s,
        m1_wmv + (size_t)l * 32 * 16 * 9, m1_wsm + (size_t)l * 32 * 32,
        m1_wms + (size_t)l * 64 * 16,     m1_wss + (size_t)l * 64 * 32,
        m2_wmv + (size_t)l * 16 * 16 * 9, m2_wsm + (size_t)l * 16 * 32,
        m2_wms + (size_t)l * 32 * 16,     m2_wss + (size_t)l * 32 * 32);
  }

  k_final<<<BB, 256, 0, stream>>>(mv, s, wout_mv, wout_sm, out);

  (void)in_sizes; (void)n_in; (void)out_size; (void)ws_size;
}